// Round 8
// baseline (379.652 us; speedup 1.0000x reference)
//
#include <hip/hip_runtime.h>
#include <math.h>

#define HH 96
#define WW 96
#define LL 9216          // H*W
#define D9 288           // 32 q-channels * 9 taps
#define TOPK 5
#define NK 6             // per-split list length
#define NCAND 8          // fp32 re-rank candidates
#define KSPLIT 32
#define CPQ (KSPLIT * NK)                // 192 packed entries per query
#define KEYS_PER_SPLIT (LL / KSPLIT)     // 288
#define PASSES (KEYS_PER_SPLIT / 32)     // 9
#define CHUNKS (32 * 36)                 // 16B chunks per 32-key pass
#define KROW 292                         // LDS row stride in bf16 elems (584B, 2-way banks)

typedef short short8 __attribute__((ext_vector_type(8)));
typedef float f32x16 __attribute__((ext_vector_type(16)));

__device__ __forceinline__ float  asf(unsigned u) { union { unsigned u; float f; } a; a.u = u; return a.f; }
__device__ __forceinline__ unsigned asu(float f)  { union { float f; unsigned u; } a; a.f = f; return a.u; }

__device__ __forceinline__ unsigned short f2bf(float f) {
    unsigned u = asu(f);
    unsigned r = u + 0x7fff + ((u >> 16) & 1);   // RNE
    return (unsigned short)(r >> 16);
}

// sorted-desc top-N insert via med3: zero serial depth, N ops.
template<int N>
__device__ __forceinline__ void ins_med3(float* v, float x) {
    float nv[N];
    nv[0] = fmaxf(v[0], x);
    #pragma unroll
    for (int s = 1; s < N; ++s) nv[s] = __builtin_amdgcn_fmed3f(v[s-1], v[s], x);
    #pragma unroll
    for (int s = 0; s < N; ++s) v[s] = nv[s];
}

__device__ __forceinline__ bool better_tb(float av, int ai, float bv, int bi) {
    return (av > bv) || (av == bv && ai < bi);
}

template<int N>
__device__ __forceinline__ void insert_tb(float (&v)[N], int (&ix)[N], float nv, int ni) {
    if (better_tb(nv, ni, v[N-1], ix[N-1])) {
        v[N-1] = nv; ix[N-1] = ni;
        #pragma unroll
        for (int s = N-1; s > 0; --s) {
            if (better_tb(v[s], ix[s], v[s-1], ix[s-1])) {
                float tv = v[s]; v[s] = v[s-1]; v[s-1] = tv;
                int ti = ix[s]; ix[s] = ix[s-1]; ix[s-1] = ti;
            }
        }
    }
}

// ======== LDS-staged direct 3x3 conv, 8 output channels per block ========
// Tile: 6 rows x 16 ci x 98 cols (zero-padded), 4 ci-chunks. Block = 256 px.
// stage1: blockIdx.y g: 0-7 -> c1 (relu), 8-11 -> q, 12-15 -> k.
__device__ __forceinline__ void conv8_staged(
    const float* __restrict__ in, const float* __restrict__ Wt,
    const float* __restrict__ bias, float* __restrict__ out,
    int co0, int doRelu, float* lds)
{
    int tid = threadIdx.x;
    int pix = blockIdx.x * 256 + tid;
    int p_row = pix / WW, p_col = pix - p_row * WW;
    int r_lo = (blockIdx.x * 256) / WW;
    int rbase = p_row - r_lo + 1;                 // 1..4

    float acc[8];
    #pragma unroll
    for (int j = 0; j < 8; ++j) acc[j] = bias[co0 + j];

    #pragma unroll 1
    for (int chunk = 0; chunk < 4; ++chunk) {
        int ci0 = chunk * 16;
        // stage 96 segs (6 rows x 16 ci) x 96 cols, coalesced
        #pragma unroll
        for (int s = 0; s < 36; ++s) {
            int flat = s * 256 + tid;
            int seg = flat / 96, col = flat - seg * 96;
            int g_r = r_lo - 1 + (seg >> 4);
            int ci  = ci0 + (seg & 15);
            float val = ((unsigned)g_r < 96u) ? in[(size_t)ci * LL + g_r * WW + col] : 0.0f;
            lds[seg * 100 + col + 1] = val;
        }
        if (tid < 192) lds[(tid >> 1) * 100 + ((tid & 1) ? 97 : 0)] = 0.0f;
        __syncthreads();

        #pragma unroll 2
        for (int ci = 0; ci < 16; ++ci) {
            float v9[9];
            #pragma unroll
            for (int u = 0; u < 3; ++u)
                #pragma unroll
                for (int v = 0; v < 3; ++v)
                    v9[u*3+v] = lds[((rbase + u - 1) * 16 + ci) * 100 + p_col + v];
            const float* wb = Wt + ((size_t)co0 * 64 + (ci0 + ci)) * 9;
            #pragma unroll
            for (int j = 0; j < 8; ++j) {
                const float* wp = wb + (size_t)j * 64 * 9;
                #pragma unroll
                for (int t = 0; t < 9; ++t) acc[j] = fmaf(v9[t], wp[t], acc[j]);
            }
        }
        __syncthreads();
    }
    #pragma unroll
    for (int j = 0; j < 8; ++j) {
        float r = doRelu ? fmaxf(acc[j], 0.0f) : acc[j];
        out[(size_t)(co0 + j) * LL + pix] = r;
    }
}

__global__ __launch_bounds__(256) void conv_stage1_kernel(
    const float* __restrict__ x,
    const float* __restrict__ W1, const float* __restrict__ b1, float* __restrict__ c1,
    const float* __restrict__ Wq, const float* __restrict__ bq,
    const float* __restrict__ Wk, const float* __restrict__ bk,
    float* __restrict__ qq, float* __restrict__ kk)
{
    __shared__ float lds[6 * 16 * 100];
    int g = blockIdx.y;
    if (g < 8)       conv8_staged(x, W1, b1, c1, g * 8,        1, lds);
    else if (g < 12) conv8_staged(x, Wq, bq, qq, (g - 8) * 8,  0, lds);
    else             conv8_staged(x, Wk, bk, kk, (g - 12) * 8, 0, lds);
}

__global__ __launch_bounds__(256) void conv2_kernel(
    const float* __restrict__ c1, const float* __restrict__ W2,
    const float* __restrict__ b2, float* __restrict__ feat)
{
    __shared__ float lds[6 * 16 * 100];
    conv8_staged(c1, W2, b2, feat, blockIdx.y * 8, 1, lds);
}

// ---------------- transpose x: [64][LL] -> xT [LL][64] (for coalesced gather) ----------------
__global__ __launch_bounds__(256) void transpose_x_kernel(
    const float* __restrict__ x, float* __restrict__ xT)
{
    __shared__ float t[64][65];
    int pix0 = blockIdx.x * 64;
    int lp = threadIdx.x & 63, cg = threadIdx.x >> 6;
    #pragma unroll
    for (int cc = 0; cc < 16; ++cc) {
        int c = cg * 16 + cc;
        t[c][lp] = x[(size_t)c * LL + pix0 + lp];
    }
    __syncthreads();
    #pragma unroll
    for (int pp = 0; pp < 16; ++pp) {
        int pl = cg * 16 + pp;
        xT[(size_t)(pix0 + pl) * 64 + lp] = t[lp][pl];
    }
}

// ------ unfold3 + L2-normalize; LDS-staged tile, [L][288] fp32 + bf16, coalesced ------
__global__ __launch_bounds__(256) void unfold_norm_kernel(
    const float* __restrict__ qq, float* __restrict__ q_f32, unsigned short* __restrict__ q_bf,
    const float* __restrict__ kk, float* __restrict__ k_f32, unsigned short* __restrict__ k_bf)
{
    const float* in; float* o32; unsigned short* obf;
    if (blockIdx.y == 0) { in = qq; o32 = q_f32; obf = q_bf; }
    else                 { in = kk; o32 = k_f32; obf = k_bf; }

    __shared__ float tile[3][32][34];   // [row][chan][col]
    __shared__ float inv_s[32];
    int tid = threadIdx.x;
    int l0 = blockIdx.x * 32;
    int y = l0 / WW, xb = l0 % WW;

    #pragma unroll
    for (int j = 0; j < 13; ++j) {
        int f = j * 256 + tid;
        if (f < 3 * 32 * 34) {
            int col = f % 34, cc = (f / 34) & 31, r = f / (34 * 32);
            int yy = y + r - 1, xv = xb + col - 1;
            float val = ((unsigned)yy < 96u && (unsigned)xv < 96u)
                        ? in[(size_t)cc * LL + yy * 96 + xv] : 0.0f;
            tile[r][cc][col] = val;
        }
    }
    __syncthreads();

    {
        int pxl = tid >> 3, sub = tid & 7;
        float ss = 0.0f;
        #pragma unroll
        for (int cc = 0; cc < 4; ++cc) {
            int c = sub * 4 + cc;
            #pragma unroll
            for (int u = 0; u < 3; ++u)
                #pragma unroll
                for (int v = 0; v < 3; ++v) {
                    float val = tile[u][c][pxl + v];
                    ss = fmaf(val, val, ss);
                }
        }
        ss += __shfl_xor(ss, 1);
        ss += __shfl_xor(ss, 2);
        ss += __shfl_xor(ss, 4);
        if (sub == 0) inv_s[pxl] = 1.0f / fmaxf(sqrtf(ss), 1e-12f);
    }
    __syncthreads();

    #pragma unroll 1
    for (int it = 0; it < 9; ++it) {
        int e = it * 256 + tid;
        int pxl = e / 72, dc = e - pxl * 72;
        int l = l0 + pxl;
        float inv = inv_s[pxl];
        float4 o; float* op = &o.x;
        #pragma unroll
        for (int i = 0; i < 4; ++i) {
            int d = dc * 4 + i;
            int c = d / 9, rm = d - c * 9;
            int u = rm / 3, v = rm - u * 3;
            op[i] = tile[u][c][pxl + v] * inv;
        }
        *(float4*)(o32 + (size_t)l * D9 + dc * 4) = o;
        unsigned short b4[4];
        #pragma unroll
        for (int i = 0; i < 4; ++i) b4[i] = f2bf(op[i]);
        *(uint2*)(obf + (size_t)l * D9 + dc * 4) = *(uint2*)b4;
    }
}

// ---------------- MFMA similarity + med3-packed streaming top-6 per key-split ----------------
__global__ __launch_bounds__(256, 2) void topk_mfma_kernel(
    const unsigned short* __restrict__ qn_bf, const unsigned short* __restrict__ kn_bf,
    float* __restrict__ valsQ)
{
    __shared__ unsigned short ks[2][32 * KROW];

    int tid  = threadIdx.x;
    int lane = tid & 63;
    int col = lane & 31, khalf = lane >> 5;
    int qtile = blockIdx.x >> 5;
    int split = blockIdx.x & 31;
    int q0w = qtile * 256 + (tid >> 6) * 64;
    int key0 = split * KEYS_PER_SPLIT;

    short8 qf[2][18];
    #pragma unroll
    for (int b = 0; b < 2; ++b) {
        const unsigned short* qrow = qn_bf + (size_t)(q0w + b*32 + col) * D9 + khalf * 8;
        #pragma unroll
        for (int dg = 0; dg < 18; ++dg)
            qf[b][dg] = *(const short8*)(qrow + dg * 16);
    }

    float lv0[NK], lv1[NK];
    #pragma unroll
    for (int s = 0; s < NK; ++s) { lv0[s] = -INFINITY; lv1[s] = -INFINITY; }

    const char* kg = (const char*)kn_bf;
    uint4 pre[5];

    #pragma unroll
    for (int c0 = 0; c0 < 5; ++c0) {
        int c = tid + c0 * 256;
        if (c < CHUNKS) {
            int key = c / 36, off = c - key * 36;
            pre[c0] = *(const uint4*)(kg + (size_t)(key0 + key) * 576 + off * 16);
        }
    }
    #pragma unroll
    for (int c0 = 0; c0 < 5; ++c0) {
        int c = tid + c0 * 256;
        if (c < CHUNKS) {
            int key = c / 36, off = c - key * 36;
            char* d = (char*)ks[0] + key * (KROW*2) + off * 16;
            *(uint2*)d       = *(uint2*)&pre[c0];
            *(uint2*)(d + 8) = *((uint2*)&pre[c0] + 1);
        }
    }
    __syncthreads();

    for (int p = 0; p < PASSES; ++p) {
        if (p + 1 < PASSES) {
            #pragma unroll
            for (int c0 = 0; c0 < 5; ++c0) {
                int c = tid + c0 * 256;
                if (c < CHUNKS) {
                    int key = c / 36, off = c - key * 36;
                    pre[c0] = *(const uint4*)(kg + (size_t)(key0 + (p+1)*32 + key) * 576 + off * 16);
                }
            }
        }

        f32x16 acc0 = {}, acc1 = {};
        const char* kb = (const char*)ks[p & 1] + (size_t)col * (KROW*2) + khalf * 16;
        #pragma unroll
        for (int dg = 0; dg < 18; ++dg) {
            short8 af;
            *(uint2*)&af       = *(const uint2*)(kb + dg * 32);
            *((uint2*)&af + 1) = *(const uint2*)(kb + dg * 32 + 8);
            acc0 = __builtin_amdgcn_mfma_f32_32x32x16_bf16(af, qf[0][dg], acc0, 0, 0, 0);
            acc1 = __builtin_amdgcn_mfma_f32_32x32x16_bf16(af, qf[1][dg], acc1, 0, 0, 0);
        }

        int lbase = p * 32 + 4 * khalf;
        #pragma unroll
        for (int r = 0; r < 16; ++r) {
            unsigned lkey = (unsigned)(lbase + (r & 3) + 8 * (r >> 2));
            ins_med3<NK>(lv0, asf((asu(acc0[r]) & 0xFFFFFE00u) | lkey));
            ins_med3<NK>(lv1, asf((asu(acc1[r]) & 0xFFFFFE00u) | lkey));
        }

        if (p + 1 < PASSES) {
            #pragma unroll
            for (int c0 = 0; c0 < 5; ++c0) {
                int c = tid + c0 * 256;
                if (c < CHUNKS) {
                    int key = c / 36, off = c - key * 36;
                    char* d = (char*)ks[(p+1) & 1] + key * (KROW*2) + off * 16;
                    *(uint2*)d       = *(uint2*)&pre[c0];
                    *(uint2*)(d + 8) = *((uint2*)&pre[c0] + 1);
                }
            }
        }
        __syncthreads();
    }

    #pragma unroll
    for (int b = 0; b < 2; ++b) {
        float* lv = b ? lv1 : lv0;
        float pv[NK];
        #pragma unroll
        for (int s = 0; s < NK; ++s) pv[s] = __shfl_xor(lv[s], 32);
        #pragma unroll
        for (int s = 0; s < NK; ++s) ins_med3<NK>(lv, pv[s]);
        if (lane < 32) {
            int q = q0w + b * 32 + col;
            float* vq = valsQ + (size_t)q * CPQ + split * NK;
            #pragma unroll
            for (int s = 0; s < NK; ++s) vq[s] = lv[s];
        }
    }
}

// -------- 32 lanes/query: packed merge -> top-8 candidates -> exact fp32 re-rank --------
__global__ __launch_bounds__(256) void rerank_kernel(
    const float* __restrict__ valsQ,
    const float* __restrict__ qn_f32, const float* __restrict__ kn_f32,
    float* __restrict__ vals, int* __restrict__ idxs)
{
    int tid = threadIdx.x;
    int lane = tid & 63;
    int half = lane >> 5, l32 = lane & 31;
    int q = blockIdx.x * 8 + (tid >> 6) * 2 + half;

    const float* vq = valsQ + (size_t)q * CPQ + l32 * NK;
    float v[NK];
    #pragma unroll
    for (int s = 0; s < NK; ++s) v[s] = vq[s];

    int ckey[NCAND];
    #pragma unroll
    for (int it = 0; it < NCAND; ++it) {
        float cv = v[0];
        int cl = l32;
        #pragma unroll
        for (int st = 1; st < 32; st <<= 1) {
            float ov = __shfl_xor(cv, st);
            int ol = __shfl_xor(cl, st);
            if (ov > cv || (ov == cv && ol < cl)) { cv = ov; cl = ol; }
        }
        ckey[it] = cl * KEYS_PER_SPLIT + (int)(asu(cv) & 0x1FFu);
        if (cl == l32) {
            #pragma unroll
            for (int s = 0; s < NK-1; ++s) v[s] = v[s+1];
            v[NK-1] = -INFINITY;
        }
    }

    int r = l32 >> 2, part = l32 & 3;
    const float4* qr = (const float4*)(qn_f32 + (size_t)q * D9) + part * 18;
    const float4* kr = (const float4*)(kn_f32 + (size_t)ckey[r] * D9) + part * 18;
    float s0 = 0.f, s1 = 0.f, s2 = 0.f, s3 = 0.f;
    #pragma unroll
    for (int i2 = 0; i2 < 18; ++i2) {
        float4 a = qr[i2], b = kr[i2];
        s0 = fmaf(a.x, b.x, s0); s1 = fmaf(a.y, b.y, s1);
        s2 = fmaf(a.z, b.z, s2); s3 = fmaf(a.w, b.w, s3);
    }
    float sc = (s0 + s1) + (s2 + s3);
    sc += __shfl_xor(sc, 1);
    sc += __shfl_xor(sc, 2);

    float bv[TOPK]; int bi[TOPK];
    #pragma unroll
    for (int s = 0; s < TOPK; ++s) { bv[s] = -INFINITY; bi[s] = 0x7fffffff; }
    #pragma unroll
    for (int cc = 0; cc < NCAND; ++cc) {
        float sv = __shfl(sc, half * 32 + cc * 4);
        insert_tb<TOPK>(bv, bi, sv, ckey[cc]);
    }
    if (l32 == 0) {
        #pragma unroll
        for (int s = 0; s < TOPK; ++s) {
            vals[(size_t)s * LL + q] = bv[s];
            idxs[(size_t)s * LL + q] = bi[s];
        }
    }
}

// ------------- epilogue: wave-per-pixel, lanes over channels, coalesced gathers -------------
__global__ __launch_bounds__(256) void gather_out_kernel(
    const float* __restrict__ xT, const float* __restrict__ feat,
    const float* __restrict__ vals, const int* __restrict__ idxs,
    float* __restrict__ out)
{
    int wave = threadIdx.x >> 6, lane = threadIdx.x & 63;
    int pix = blockIdx.x * 4 + wave;
    int y = pix / WW, x0 = pix - y * WW;
    float acc = 0.0f;
    #pragma unroll 1
    for (int s = 1; s < TOPK; ++s) {
        float S = vals[(size_t)s * LL + pix] * (1.0f/9.0f);
        #pragma unroll
        for (int i = 0; i < 3; ++i) {
            int qy = y + 1 - i;
            #pragma unroll
            for (int j = 0; j < 3; ++j) {
                int qx = x0 + 1 - j;
                if ((unsigned)qy < 96u && (unsigned)qx < 96u) {
                    int l = idxs[(size_t)s * LL + qy * WW + qx];
                    int yl = l / WW, xl = l - yl * WW;
                    int sy = yl + i - 1, sx = xl + j - 1;
                    if ((unsigned)sy < 96u && (unsigned)sx < 96u)
                        acc = fmaf(S, xT[(size_t)(sy * WW + sx) * 64 + lane], acc);
                }
            }
        }
    }
    out[(size_t)lane * LL + pix] = feat[(size_t)lane * LL + pix]
                                 + xT[(size_t)pix * 64 + lane] + acc * 0.25f;
}

extern "C" void kernel_launch(void* const* d_in, const int* in_sizes, int n_in,
                              void* d_out, int out_size, void* d_ws, size_t ws_size,
                              hipStream_t stream)
{
    (void)in_sizes; (void)n_in; (void)out_size; (void)ws_size;
    const float* x  = (const float*)d_in[0];
    const float* W1 = (const float*)d_in[1];
    const float* b1 = (const float*)d_in[2];
    const float* W2 = (const float*)d_in[3];
    const float* b2 = (const float*)d_in[4];
    const float* Wq = (const float*)d_in[5];
    const float* bq = (const float*)d_in[6];
    const float* Wk = (const float*)d_in[7];
    const float* bk = (const float*)d_in[8];
    float* out = (float*)d_out;

    char* p = (char*)d_ws;
    float* c1     = (float*)p;            p += (size_t)64 * LL * 4;
    float* feat   = (float*)p;            p += (size_t)64 * LL * 4;
    float* xT     = (float*)p;            p += (size_t)64 * LL * 4;
    float* qq     = (float*)p;            p += (size_t)32 * LL * 4;
    float* kk     = (float*)p;            p += (size_t)32 * LL * 4;
    float* qn_f32 = (float*)p;            p += (size_t)LL * D9 * 4;
    float* kn_f32 = (float*)p;            p += (size_t)LL * D9 * 4;
    unsigned short* qn_bf = (unsigned short*)p;  p += (size_t)LL * D9 * 2;
    unsigned short* kn_bf = (unsigned short*)p;  p += (size_t)LL * D9 * 2;
    float* valsQ  = (float*)p;            p += (size_t)LL * CPQ * 4;
    float* vals   = (float*)p;            p += (size_t)TOPK * LL * 4;
    int*   idxs   = (int*)p;              p += (size_t)TOPK * LL * 4;

    conv_stage1_kernel<<<dim3(36, 16), 256, 0, stream>>>(x, W1, b1, c1, Wq, bq, Wk, bk, qq, kk);
    unfold_norm_kernel<<<dim3(288, 2), 256, 0, stream>>>(qq, qn_f32, qn_bf, kk, kn_f32, kn_bf);
    topk_mfma_kernel<<<36 * KSPLIT, 256, 0, stream>>>(qn_bf, kn_bf, valsQ);
    conv2_kernel<<<dim3(36, 8), 256, 0, stream>>>(c1, W2, b2, feat);
    transpose_x_kernel<<<144, 256, 0, stream>>>(x, xT);
    rerank_kernel<<<LL / 8, 256, 0, stream>>>(valsQ, qn_f32, kn_f32, vals, idxs);
    gather_out_kernel<<<LL / 4, 256, 0, stream>>>(xT, feat, vals, idxs, out);
}

// Round 9
// 354.390 us; speedup vs baseline: 1.0713x; 1.0713x over previous
//
#include <hip/hip_runtime.h>
#include <math.h>

#define HH 96
#define WW 96
#define LL 9216          // H*W
#define D9 288           // 32 q-channels * 9 taps
#define TOPK 5
#define NK 6             // per-split list length
#define NCAND 8          // fp32 re-rank candidates
#define KSPLIT 32
#define CPQ (KSPLIT * NK)                // 192 packed entries per query
#define KEYS_PER_SPLIT (LL / KSPLIT)     // 288
#define PASSES (KEYS_PER_SPLIT / 32)     // 9
#define CHUNKS (32 * 36)                 // 16B chunks per 32-key pass
#define KROW 292                         // LDS row stride in bf16 elems (584B, 2-way banks)

typedef short short8 __attribute__((ext_vector_type(8)));
typedef float f32x16 __attribute__((ext_vector_type(16)));

__device__ __forceinline__ float  asf(unsigned u) { union { unsigned u; float f; } a; a.u = u; return a.f; }
__device__ __forceinline__ unsigned asu(float f)  { union { float f; unsigned u; } a; a.f = f; return a.u; }

__device__ __forceinline__ unsigned short f2bf(float f) {
    unsigned u = asu(f);
    unsigned r = u + 0x7fff + ((u >> 16) & 1);   // RNE
    return (unsigned short)(r >> 16);
}

// sorted-desc top-N insert via med3: zero serial depth, N ops.
template<int N>
__device__ __forceinline__ void ins_med3(float* v, float x) {
    float nv[N];
    nv[0] = fmaxf(v[0], x);
    #pragma unroll
    for (int s = 1; s < N; ++s) nv[s] = __builtin_amdgcn_fmed3f(v[s-1], v[s], x);
    #pragma unroll
    for (int s = 0; s < N; ++s) v[s] = nv[s];
}

__device__ __forceinline__ bool better_tb(float av, int ai, float bv, int bi) {
    return (av > bv) || (av == bv && ai < bi);
}

template<int N>
__device__ __forceinline__ void insert_tb(float (&v)[N], int (&ix)[N], float nv, int ni) {
    if (better_tb(nv, ni, v[N-1], ix[N-1])) {
        v[N-1] = nv; ix[N-1] = ni;
        #pragma unroll
        for (int s = N-1; s > 0; --s) {
            if (better_tb(v[s], ix[s], v[s-1], ix[s-1])) {
                float tv = v[s]; v[s] = v[s-1]; v[s-1] = tv;
                int ti = ix[s]; ix[s] = ix[s-1]; ix[s-1] = ti;
            }
        }
    }
}

// ======== direct 3x3 conv, registers only: 2 consecutive px x 4 co per thread ========
// WW=96 even -> a 2-px pair never crosses a row. 12 guarded loads per ci feed 72 FMAs.
__device__ __forceinline__ void conv2px4co(
    const float* __restrict__ in, const float* __restrict__ Wt,
    const float* __restrict__ bias, float* __restrict__ out,
    int co0, int doRelu)
{
    int pix0 = (blockIdx.x * 256 + threadIdx.x) * 2;   // 18*256*2 == 9216
    int y = pix0 / WW, x0 = pix0 - y * WW;             // x0 even, 0..94
    bool mL = (x0 > 0), mR = (x0 < 94);

    float acc[4][2];
    #pragma unroll
    for (int j = 0; j < 4; ++j) acc[j][0] = acc[j][1] = bias[co0 + j];

    #pragma unroll 2
    for (int ci = 0; ci < 64; ++ci) {
        const float* xp = in + (size_t)ci * LL;
        float r[3][4];
        #pragma unroll
        for (int u = 0; u < 3; ++u) {
            int yy = y + u - 1;
            bool yok = (unsigned)yy < 96u;
            const float* row = xp + yy * WW + x0;
            r[u][0] = (yok && mL) ? row[-1] : 0.0f;
            r[u][1] = yok ? row[0] : 0.0f;
            r[u][2] = yok ? row[1] : 0.0f;
            r[u][3] = (yok && mR) ? row[2] : 0.0f;
        }
        const float* wb = Wt + ((size_t)co0 * 64 + ci) * 9;
        #pragma unroll
        for (int j = 0; j < 4; ++j) {
            const float* wp = wb + (size_t)j * 64 * 9;
            #pragma unroll
            for (int u = 0; u < 3; ++u)
                #pragma unroll
                for (int v = 0; v < 3; ++v) {
                    float w = wp[u*3+v];
                    acc[j][0] = fmaf(r[u][v],     w, acc[j][0]);
                    acc[j][1] = fmaf(r[u][v + 1], w, acc[j][1]);
                }
        }
    }
    #pragma unroll
    for (int j = 0; j < 4; ++j) {
        float2 o;
        o.x = doRelu ? fmaxf(acc[j][0], 0.0f) : acc[j][0];
        o.y = doRelu ? fmaxf(acc[j][1], 0.0f) : acc[j][1];
        *(float2*)(out + (size_t)(co0 + j) * LL + pix0) = o;   // 8B coalesced
    }
}

// stage1: g 0-15 -> c1 (relu), 16-23 -> q, 24-31 -> k
__global__ __launch_bounds__(256) void conv_stage1_kernel(
    const float* __restrict__ x,
    const float* __restrict__ W1, const float* __restrict__ b1, float* __restrict__ c1,
    const float* __restrict__ Wq, const float* __restrict__ bq,
    const float* __restrict__ Wk, const float* __restrict__ bk,
    float* __restrict__ qq, float* __restrict__ kk)
{
    int g = blockIdx.y;
    if (g < 16)      conv2px4co(x, W1, b1, c1, g * 4,        1);
    else if (g < 24) conv2px4co(x, Wq, bq, qq, (g - 16) * 4, 0);
    else             conv2px4co(x, Wk, bk, kk, (g - 24) * 4, 0);
}

__global__ __launch_bounds__(256) void conv2_kernel(
    const float* __restrict__ c1, const float* __restrict__ W2,
    const float* __restrict__ b2, float* __restrict__ feat)
{
    conv2px4co(c1, W2, b2, feat, blockIdx.y * 4, 1);
}

// ---------------- transpose x: [64][LL] -> xT [LL][64] (for coalesced gather) ----------------
__global__ __launch_bounds__(256) void transpose_x_kernel(
    const float* __restrict__ x, float* __restrict__ xT)
{
    __shared__ float t[64][65];
    int pix0 = blockIdx.x * 64;
    int lp = threadIdx.x & 63, cg = threadIdx.x >> 6;
    #pragma unroll
    for (int cc = 0; cc < 16; ++cc) {
        int c = cg * 16 + cc;
        t[c][lp] = x[(size_t)c * LL + pix0 + lp];
    }
    __syncthreads();
    #pragma unroll
    for (int pp = 0; pp < 16; ++pp) {
        int pl = cg * 16 + pp;
        xT[(size_t)(pix0 + pl) * 64 + lp] = t[lp][pl];
    }
}

// ------ unfold3 + L2-normalize; LDS-staged tile, [L][288] fp32 + bf16, coalesced ------
__global__ __launch_bounds__(256) void unfold_norm_kernel(
    const float* __restrict__ qq, float* __restrict__ q_f32, unsigned short* __restrict__ q_bf,
    const float* __restrict__ kk, float* __restrict__ k_f32, unsigned short* __restrict__ k_bf)
{
    const float* in; float* o32; unsigned short* obf;
    if (blockIdx.y == 0) { in = qq; o32 = q_f32; obf = q_bf; }
    else                 { in = kk; o32 = k_f32; obf = k_bf; }

    __shared__ float tile[3][32][34];   // [row][chan][col]
    __shared__ float inv_s[32];
    int tid = threadIdx.x;
    int l0 = blockIdx.x * 32;
    int y = l0 / WW, xb = l0 % WW;

    #pragma unroll
    for (int j = 0; j < 13; ++j) {
        int f = j * 256 + tid;
        if (f < 3 * 32 * 34) {
            int col = f % 34, cc = (f / 34) & 31, r = f / (34 * 32);
            int yy = y + r - 1, xv = xb + col - 1;
            float val = ((unsigned)yy < 96u && (unsigned)xv < 96u)
                        ? in[(size_t)cc * LL + yy * 96 + xv] : 0.0f;
            tile[r][cc][col] = val;
        }
    }
    __syncthreads();

    {
        int pxl = tid >> 3, sub = tid & 7;
        float ss = 0.0f;
        #pragma unroll
        for (int cc = 0; cc < 4; ++cc) {
            int c = sub * 4 + cc;
            #pragma unroll
            for (int u = 0; u < 3; ++u)
                #pragma unroll
                for (int v = 0; v < 3; ++v) {
                    float val = tile[u][c][pxl + v];
                    ss = fmaf(val, val, ss);
                }
        }
        ss += __shfl_xor(ss, 1);
        ss += __shfl_xor(ss, 2);
        ss += __shfl_xor(ss, 4);
        if (sub == 0) inv_s[pxl] = 1.0f / fmaxf(sqrtf(ss), 1e-12f);
    }
    __syncthreads();

    #pragma unroll 1
    for (int it = 0; it < 9; ++it) {
        int e = it * 256 + tid;
        int pxl = e / 72, dc = e - pxl * 72;
        int l = l0 + pxl;
        float inv = inv_s[pxl];
        float4 o; float* op = &o.x;
        #pragma unroll
        for (int i = 0; i < 4; ++i) {
            int d = dc * 4 + i;
            int c = d / 9, rm = d - c * 9;
            int u = rm / 3, v = rm - u * 3;
            op[i] = tile[u][c][pxl + v] * inv;
        }
        *(float4*)(o32 + (size_t)l * D9 + dc * 4) = o;
        unsigned short b4[4];
        #pragma unroll
        for (int i = 0; i < 4; ++i) b4[i] = f2bf(op[i]);
        *(uint2*)(obf + (size_t)l * D9 + dc * 4) = *(uint2*)b4;
    }
}

// ---------------- MFMA similarity + med3-packed streaming top-6 per key-split ----------------
__global__ __launch_bounds__(256, 2) void topk_mfma_kernel(
    const unsigned short* __restrict__ qn_bf, const unsigned short* __restrict__ kn_bf,
    float* __restrict__ valsQ)
{
    __shared__ unsigned short ks[2][32 * KROW];

    int tid  = threadIdx.x;
    int lane = tid & 63;
    int col = lane & 31, khalf = lane >> 5;
    int qtile = blockIdx.x >> 5;
    int split = blockIdx.x & 31;
    int q0w = qtile * 256 + (tid >> 6) * 64;
    int key0 = split * KEYS_PER_SPLIT;

    short8 qf[2][18];
    #pragma unroll
    for (int b = 0; b < 2; ++b) {
        const unsigned short* qrow = qn_bf + (size_t)(q0w + b*32 + col) * D9 + khalf * 8;
        #pragma unroll
        for (int dg = 0; dg < 18; ++dg)
            qf[b][dg] = *(const short8*)(qrow + dg * 16);
    }

    float lv0[NK], lv1[NK];
    #pragma unroll
    for (int s = 0; s < NK; ++s) { lv0[s] = -INFINITY; lv1[s] = -INFINITY; }

    const char* kg = (const char*)kn_bf;
    uint4 pre[5];

    #pragma unroll
    for (int c0 = 0; c0 < 5; ++c0) {
        int c = tid + c0 * 256;
        if (c < CHUNKS) {
            int key = c / 36, off = c - key * 36;
            pre[c0] = *(const uint4*)(kg + (size_t)(key0 + key) * 576 + off * 16);
        }
    }
    #pragma unroll
    for (int c0 = 0; c0 < 5; ++c0) {
        int c = tid + c0 * 256;
        if (c < CHUNKS) {
            int key = c / 36, off = c - key * 36;
            char* d = (char*)ks[0] + key * (KROW*2) + off * 16;
            *(uint2*)d       = *(uint2*)&pre[c0];
            *(uint2*)(d + 8) = *((uint2*)&pre[c0] + 1);
        }
    }
    __syncthreads();

    for (int p = 0; p < PASSES; ++p) {
        if (p + 1 < PASSES) {
            #pragma unroll
            for (int c0 = 0; c0 < 5; ++c0) {
                int c = tid + c0 * 256;
                if (c < CHUNKS) {
                    int key = c / 36, off = c - key * 36;
                    pre[c0] = *(const uint4*)(kg + (size_t)(key0 + (p+1)*32 + key) * 576 + off * 16);
                }
            }
        }

        f32x16 acc0 = {}, acc1 = {};
        const char* kb = (const char*)ks[p & 1] + (size_t)col * (KROW*2) + khalf * 16;
        #pragma unroll
        for (int dg = 0; dg < 18; ++dg) {
            short8 af;
            *(uint2*)&af       = *(const uint2*)(kb + dg * 32);
            *((uint2*)&af + 1) = *(const uint2*)(kb + dg * 32 + 8);
            acc0 = __builtin_amdgcn_mfma_f32_32x32x16_bf16(af, qf[0][dg], acc0, 0, 0, 0);
            acc1 = __builtin_amdgcn_mfma_f32_32x32x16_bf16(af, qf[1][dg], acc1, 0, 0, 0);
        }

        int lbase = p * 32 + 4 * khalf;
        #pragma unroll
        for (int r = 0; r < 16; ++r) {
            unsigned lkey = (unsigned)(lbase + (r & 3) + 8 * (r >> 2));
            ins_med3<NK>(lv0, asf((asu(acc0[r]) & 0xFFFFFE00u) | lkey));
            ins_med3<NK>(lv1, asf((asu(acc1[r]) & 0xFFFFFE00u) | lkey));
        }

        if (p + 1 < PASSES) {
            #pragma unroll
            for (int c0 = 0; c0 < 5; ++c0) {
                int c = tid + c0 * 256;
                if (c < CHUNKS) {
                    int key = c / 36, off = c - key * 36;
                    char* d = (char*)ks[(p+1) & 1] + key * (KROW*2) + off * 16;
                    *(uint2*)d       = *(uint2*)&pre[c0];
                    *(uint2*)(d + 8) = *((uint2*)&pre[c0] + 1);
                }
            }
        }
        __syncthreads();
    }

    #pragma unroll
    for (int b = 0; b < 2; ++b) {
        float* lv = b ? lv1 : lv0;
        float pv[NK];
        #pragma unroll
        for (int s = 0; s < NK; ++s) pv[s] = __shfl_xor(lv[s], 32);
        #pragma unroll
        for (int s = 0; s < NK; ++s) ins_med3<NK>(lv, pv[s]);
        if (lane < 32) {
            int q = q0w + b * 32 + col;
            float* vq = valsQ + (size_t)q * CPQ + split * NK;
            #pragma unroll
            for (int s = 0; s < NK; ++s) vq[s] = lv[s];
        }
    }
}

// -------- 32 lanes/query: packed merge -> top-8 candidates -> exact fp32 re-rank --------
__global__ __launch_bounds__(256) void rerank_kernel(
    const float* __restrict__ valsQ,
    const float* __restrict__ qn_f32, const float* __restrict__ kn_f32,
    float* __restrict__ vals, int* __restrict__ idxs)
{
    int tid = threadIdx.x;
    int lane = tid & 63;
    int half = lane >> 5, l32 = lane & 31;
    int q = blockIdx.x * 8 + (tid >> 6) * 2 + half;

    const float* vq = valsQ + (size_t)q * CPQ + l32 * NK;
    float v[NK];
    #pragma unroll
    for (int s = 0; s < NK; ++s) v[s] = vq[s];

    int ckey[NCAND];
    #pragma unroll
    for (int it = 0; it < NCAND; ++it) {
        float cv = v[0];
        int cl = l32;
        #pragma unroll
        for (int st = 1; st < 32; st <<= 1) {
            float ov = __shfl_xor(cv, st);
            int ol = __shfl_xor(cl, st);
            if (ov > cv || (ov == cv && ol < cl)) { cv = ov; cl = ol; }
        }
        ckey[it] = cl * KEYS_PER_SPLIT + (int)(asu(cv) & 0x1FFu);
        if (cl == l32) {
            #pragma unroll
            for (int s = 0; s < NK-1; ++s) v[s] = v[s+1];
            v[NK-1] = -INFINITY;
        }
    }

    int r = l32 >> 2, part = l32 & 3;
    const float4* qr = (const float4*)(qn_f32 + (size_t)q * D9) + part * 18;
    const float4* kr = (const float4*)(kn_f32 + (size_t)ckey[r] * D9) + part * 18;
    float s0 = 0.f, s1 = 0.f, s2 = 0.f, s3 = 0.f;
    #pragma unroll
    for (int i2 = 0; i2 < 18; ++i2) {
        float4 a = qr[i2], b = kr[i2];
        s0 = fmaf(a.x, b.x, s0); s1 = fmaf(a.y, b.y, s1);
        s2 = fmaf(a.z, b.z, s2); s3 = fmaf(a.w, b.w, s3);
    }
    float sc = (s0 + s1) + (s2 + s3);
    sc += __shfl_xor(sc, 1);
    sc += __shfl_xor(sc, 2);

    float bv[TOPK]; int bi[TOPK];
    #pragma unroll
    for (int s = 0; s < TOPK; ++s) { bv[s] = -INFINITY; bi[s] = 0x7fffffff; }
    #pragma unroll
    for (int cc = 0; cc < NCAND; ++cc) {
        float sv = __shfl(sc, half * 32 + cc * 4);
        insert_tb<TOPK>(bv, bi, sv, ckey[cc]);
    }
    if (l32 == 0) {
        #pragma unroll
        for (int s = 0; s < TOPK; ++s) {
            vals[(size_t)s * LL + q] = bv[s];
            idxs[(size_t)s * LL + q] = bi[s];
        }
    }
}

// ------------- epilogue: wave-per-pixel, lanes over channels, coalesced gathers -------------
__global__ __launch_bounds__(256) void gather_out_kernel(
    const float* __restrict__ xT, const float* __restrict__ feat,
    const float* __restrict__ vals, const int* __restrict__ idxs,
    float* __restrict__ out)
{
    int wave = threadIdx.x >> 6, lane = threadIdx.x & 63;
    int pix = blockIdx.x * 4 + wave;
    int y = pix / WW, x0 = pix - y * WW;
    float acc = 0.0f;
    #pragma unroll 1
    for (int s = 1; s < TOPK; ++s) {
        float S = vals[(size_t)s * LL + pix] * (1.0f/9.0f);
        #pragma unroll
        for (int i = 0; i < 3; ++i) {
            int qy = y + 1 - i;
            #pragma unroll
            for (int j = 0; j < 3; ++j) {
                int qx = x0 + 1 - j;
                if ((unsigned)qy < 96u && (unsigned)qx < 96u) {
                    int l = idxs[(size_t)s * LL + qy * WW + qx];
                    int yl = l / WW, xl = l - yl * WW;
                    int sy = yl + i - 1, sx = xl + j - 1;
                    if ((unsigned)sy < 96u && (unsigned)sx < 96u)
                        acc = fmaf(S, xT[(size_t)(sy * WW + sx) * 64 + lane], acc);
                }
            }
        }
    }
    out[(size_t)lane * LL + pix] = feat[(size_t)lane * LL + pix]
                                 + xT[(size_t)pix * 64 + lane] + acc * 0.25f;
}

extern "C" void kernel_launch(void* const* d_in, const int* in_sizes, int n_in,
                              void* d_out, int out_size, void* d_ws, size_t ws_size,
                              hipStream_t stream)
{
    (void)in_sizes; (void)n_in; (void)out_size; (void)ws_size;
    const float* x  = (const float*)d_in[0];
    const float* W1 = (const float*)d_in[1];
    const float* b1 = (const float*)d_in[2];
    const float* W2 = (const float*)d_in[3];
    const float* b2 = (const float*)d_in[4];
    const float* Wq = (const float*)d_in[5];
    const float* bq = (const float*)d_in[6];
    const float* Wk = (const float*)d_in[7];
    const float* bk = (const float*)d_in[8];
    float* out = (float*)d_out;

    char* p = (char*)d_ws;
    float* c1     = (float*)p;            p += (size_t)64 * LL * 4;
    float* feat   = (float*)p;            p += (size_t)64 * LL * 4;
    float* xT     = (float*)p;            p += (size_t)64 * LL * 4;
    float* qq     = (float*)p;            p += (size_t)32 * LL * 4;
    float* kk     = (float*)p;            p += (size_t)32 * LL * 4;
    float* qn_f32 = (float*)p;            p += (size_t)LL * D9 * 4;
    float* kn_f32 = (float*)p;            p += (size_t)LL * D9 * 4;
    unsigned short* qn_bf = (unsigned short*)p;  p += (size_t)LL * D9 * 2;
    unsigned short* kn_bf = (unsigned short*)p;  p += (size_t)LL * D9 * 2;
    float* valsQ  = (float*)p;            p += (size_t)LL * CPQ * 4;
    float* vals   = (float*)p;            p += (size_t)TOPK * LL * 4;
    int*   idxs   = (int*)p;              p += (size_t)TOPK * LL * 4;

    conv_stage1_kernel<<<dim3(18, 32), 256, 0, stream>>>(x, W1, b1, c1, Wq, bq, Wk, bk, qq, kk);
    unfold_norm_kernel<<<dim3(288, 2), 256, 0, stream>>>(qq, qn_f32, qn_bf, kk, kn_f32, kn_bf);
    topk_mfma_kernel<<<36 * KSPLIT, 256, 0, stream>>>(qn_bf, kn_bf, valsQ);
    conv2_kernel<<<dim3(18, 16), 256, 0, stream>>>(c1, W2, b2, feat);
    transpose_x_kernel<<<144, 256, 0, stream>>>(x, xT);
    rerank_kernel<<<LL / 8, 256, 0, stream>>>(valsQ, qn_f32, kn_f32, vals, idxs);
    gather_out_kernel<<<LL / 4, 256, 0, stream>>>(xT, feat, vals, idxs, out);
}

// Round 10
// 289.711 us; speedup vs baseline: 1.3105x; 1.2233x over previous
//
#include <hip/hip_runtime.h>
#include <math.h>

#define HH 96
#define WW 96
#define LL 9216          // H*W
#define PW 98            // padded width
#define PCH (PW * PW)    // 9604 padded floats per channel
#define D9 288           // 32 q-channels * 9 taps
#define TOPK 5
#define NK 6             // per-split list length
#define NCAND 8          // fp32 re-rank candidates
#define KSPLIT 32
#define CPQ (KSPLIT * NK)                // 192 packed entries per query
#define KEYS_PER_SPLIT (LL / KSPLIT)     // 288
#define PASSES (KEYS_PER_SPLIT / 32)     // 9
#define CHUNKS (32 * 36)                 // 16B chunks per 32-key pass
#define KROW 292                         // LDS row stride in bf16 elems (584B, 2-way banks)

typedef short short8 __attribute__((ext_vector_type(8)));
typedef float f32x16 __attribute__((ext_vector_type(16)));

__device__ __forceinline__ float  asf(unsigned u) { union { unsigned u; float f; } a; a.u = u; return a.f; }
__device__ __forceinline__ unsigned asu(float f)  { union { float f; unsigned u; } a; a.f = f; return a.u; }

__device__ __forceinline__ unsigned short f2bf(float f) {
    unsigned u = asu(f);
    unsigned r = u + 0x7fff + ((u >> 16) & 1);   // RNE
    return (unsigned short)(r >> 16);
}

// sorted-desc top-N insert via med3: zero serial depth, N ops.
template<int N>
__device__ __forceinline__ void ins_med3(float* v, float x) {
    float nv[N];
    nv[0] = fmaxf(v[0], x);
    #pragma unroll
    for (int s = 1; s < N; ++s) nv[s] = __builtin_amdgcn_fmed3f(v[s-1], v[s], x);
    #pragma unroll
    for (int s = 0; s < N; ++s) v[s] = nv[s];
}

__device__ __forceinline__ bool better_tb(float av, int ai, float bv, int bi) {
    return (av > bv) || (av == bv && ai < bi);
}

template<int N>
__device__ __forceinline__ void insert_tb(float (&v)[N], int (&ix)[N], float nv, int ni) {
    if (better_tb(nv, ni, v[N-1], ix[N-1])) {
        v[N-1] = nv; ix[N-1] = ni;
        #pragma unroll
        for (int s = N-1; s > 0; --s) {
            if (better_tb(v[s], ix[s], v[s-1], ix[s-1])) {
                float tv = v[s]; v[s] = v[s-1]; v[s-1] = tv;
                int ti = ix[s]; ix[s] = ix[s-1]; ix[s-1] = ti;
            }
        }
    }
}

// ---------------- pad-init: xpad from x (zero borders); c1pad zeroed ----------------
__global__ __launch_bounds__(256) void pad_init_kernel(
    const float* __restrict__ x, float* __restrict__ xpad, float* __restrict__ c1pad)
{
    int e = blockIdx.x * 256 + threadIdx.x;          // 2401*256 == 64*9604
    if (blockIdx.y == 1) { c1pad[e] = 0.0f; return; }
    int c = e / PCH, rem = e - c * PCH;
    int r = rem / PW, col = rem - r * PW;
    float val = 0.0f;
    if ((unsigned)(r - 1) < 96u && (unsigned)(col - 1) < 96u)
        val = x[(size_t)c * LL + (r - 1) * WW + (col - 1)];
    xpad[e] = val;
}

// ======== padded direct conv, software-pipelined: 2 px x NCO co per thread ========
// loads: 6 x 8B per ci (no guards); A/B double-buffered registers.
template<int NCO>
__device__ __forceinline__ void conv_pipe(
    const float* __restrict__ inpad, const float* __restrict__ Wt,
    const float* __restrict__ bias, int co0,
    float (&acc)[NCO][2])
{
    int t = blockIdx.x * 256 + threadIdx.x;          // 18*256 = 4608 threads
    int pix0 = t * 2;
    int y = pix0 / WW, x0 = pix0 - y * WW;           // x0 even
    const float* base = inpad + y * PW + x0;         // pad coords of (y-1, x0-1)

    #pragma unroll
    for (int j = 0; j < NCO; ++j) acc[j][0] = acc[j][1] = bias[co0 + j];

    float2 A[3][2], B[3][2];
    #pragma unroll
    for (int u = 0; u < 3; ++u) {
        A[u][0] = *(const float2*)(base + u * PW);
        A[u][1] = *(const float2*)(base + u * PW + 2);
    }

    #pragma unroll 1
    for (int ci = 0; ci < 64; ci += 2) {
        const float* nb = base + (size_t)(ci + 1) * PCH;
        #pragma unroll
        for (int u = 0; u < 3; ++u) {
            B[u][0] = *(const float2*)(nb + u * PW);
            B[u][1] = *(const float2*)(nb + u * PW + 2);
        }
        {
            const float* wb = Wt + ((size_t)co0 * 64 + ci) * 9;
            #pragma unroll
            for (int j = 0; j < NCO; ++j) {
                const float* wp = wb + (size_t)j * 64 * 9;
                #pragma unroll
                for (int u = 0; u < 3; ++u) {
                    float r0 = A[u][0].x, r1 = A[u][0].y, r2 = A[u][1].x, r3 = A[u][1].y;
                    float w0 = wp[u*3], w1 = wp[u*3+1], w2 = wp[u*3+2];
                    acc[j][0] = fmaf(r0, w0, acc[j][0]);
                    acc[j][1] = fmaf(r1, w0, acc[j][1]);
                    acc[j][0] = fmaf(r1, w1, acc[j][0]);
                    acc[j][1] = fmaf(r2, w1, acc[j][1]);
                    acc[j][0] = fmaf(r2, w2, acc[j][0]);
                    acc[j][1] = fmaf(r3, w2, acc[j][1]);
                }
            }
        }
        if (ci + 2 < 64) {
            const float* nb2 = base + (size_t)(ci + 2) * PCH;
            #pragma unroll
            for (int u = 0; u < 3; ++u) {
                A[u][0] = *(const float2*)(nb2 + u * PW);
                A[u][1] = *(const float2*)(nb2 + u * PW + 2);
            }
        }
        {
            const float* wb = Wt + ((size_t)co0 * 64 + (ci + 1)) * 9;
            #pragma unroll
            for (int j = 0; j < NCO; ++j) {
                const float* wp = wb + (size_t)j * 64 * 9;
                #pragma unroll
                for (int u = 0; u < 3; ++u) {
                    float r0 = B[u][0].x, r1 = B[u][0].y, r2 = B[u][1].x, r3 = B[u][1].y;
                    float w0 = wp[u*3], w1 = wp[u*3+1], w2 = wp[u*3+2];
                    acc[j][0] = fmaf(r0, w0, acc[j][0]);
                    acc[j][1] = fmaf(r1, w0, acc[j][1]);
                    acc[j][0] = fmaf(r1, w1, acc[j][0]);
                    acc[j][1] = fmaf(r2, w1, acc[j][1]);
                    acc[j][0] = fmaf(r2, w2, acc[j][0]);
                    acc[j][1] = fmaf(r3, w2, acc[j][1]);
                }
            }
        }
    }
}

// stage1: g 0-15 -> c1pad (relu, padded store), 16-23 -> q, 24-31 -> k
__global__ __launch_bounds__(256) void conv_stage1_kernel(
    const float* __restrict__ xpad,
    const float* __restrict__ W1, const float* __restrict__ b1, float* __restrict__ c1pad,
    const float* __restrict__ Wq, const float* __restrict__ bq,
    const float* __restrict__ Wk, const float* __restrict__ bk,
    float* __restrict__ qq, float* __restrict__ kk)
{
    int g = blockIdx.y;
    int pix0 = (blockIdx.x * 256 + threadIdx.x) * 2;
    int y = pix0 / WW, x0 = pix0 - y * WW;

    if (g < 16) {
        float acc[4][2];
        conv_pipe<4>(xpad, W1, b1, g * 4, acc);
        #pragma unroll
        for (int j = 0; j < 4; ++j) {
            float* o = c1pad + (size_t)(g * 4 + j) * PCH + (y + 1) * PW + (x0 + 1);
            o[0] = fmaxf(acc[j][0], 0.0f);
            o[1] = fmaxf(acc[j][1], 0.0f);
        }
    } else if (g < 24) {
        float acc[4][2];
        conv_pipe<4>(xpad, Wq, bq, (g - 16) * 4, acc);
        #pragma unroll
        for (int j = 0; j < 4; ++j)
            *(float2*)(qq + (size_t)((g - 16) * 4 + j) * LL + pix0) = make_float2(acc[j][0], acc[j][1]);
    } else {
        float acc[4][2];
        conv_pipe<4>(xpad, Wk, bk, (g - 24) * 4, acc);
        #pragma unroll
        for (int j = 0; j < 4; ++j)
            *(float2*)(kk + (size_t)((g - 24) * 4 + j) * LL + pix0) = make_float2(acc[j][0], acc[j][1]);
    }
}

// conv2: 2px x 2co, grid (18, 32)
__global__ __launch_bounds__(256) void conv2_kernel(
    const float* __restrict__ c1pad, const float* __restrict__ W2,
    const float* __restrict__ b2, float* __restrict__ feat)
{
    int pix0 = (blockIdx.x * 256 + threadIdx.x) * 2;
    float acc[2][2];
    conv_pipe<2>(c1pad, W2, b2, blockIdx.y * 2, acc);
    #pragma unroll
    for (int j = 0; j < 2; ++j) {
        float2 o;
        o.x = fmaxf(acc[j][0], 0.0f);
        o.y = fmaxf(acc[j][1], 0.0f);
        *(float2*)(feat + (size_t)(blockIdx.y * 2 + j) * LL + pix0) = o;
    }
}

// ---------------- transpose x: [64][LL] -> xT [LL][64] (for coalesced gather) ----------------
__global__ __launch_bounds__(256) void transpose_x_kernel(
    const float* __restrict__ x, float* __restrict__ xT)
{
    __shared__ float t[64][65];
    int pix0 = blockIdx.x * 64;
    int lp = threadIdx.x & 63, cg = threadIdx.x >> 6;
    #pragma unroll
    for (int cc = 0; cc < 16; ++cc) {
        int c = cg * 16 + cc;
        t[c][lp] = x[(size_t)c * LL + pix0 + lp];
    }
    __syncthreads();
    #pragma unroll
    for (int pp = 0; pp < 16; ++pp) {
        int pl = cg * 16 + pp;
        xT[(size_t)(pix0 + pl) * 64 + lp] = t[lp][pl];
    }
}

// ------ unfold3 + L2-normalize; LDS-staged tile, [L][288] fp32 + bf16, coalesced ------
__global__ __launch_bounds__(256) void unfold_norm_kernel(
    const float* __restrict__ qq, float* __restrict__ q_f32, unsigned short* __restrict__ q_bf,
    const float* __restrict__ kk, float* __restrict__ k_f32, unsigned short* __restrict__ k_bf)
{
    const float* in; float* o32; unsigned short* obf;
    if (blockIdx.y == 0) { in = qq; o32 = q_f32; obf = q_bf; }
    else                 { in = kk; o32 = k_f32; obf = k_bf; }

    __shared__ float tile[3][32][34];   // [row][chan][col]
    __shared__ float inv_s[32];
    int tid = threadIdx.x;
    int l0 = blockIdx.x * 32;
    int y = l0 / WW, xb = l0 % WW;

    #pragma unroll
    for (int j = 0; j < 13; ++j) {
        int f = j * 256 + tid;
        if (f < 3 * 32 * 34) {
            int col = f % 34, cc = (f / 34) & 31, r = f / (34 * 32);
            int yy = y + r - 1, xv = xb + col - 1;
            float val = ((unsigned)yy < 96u && (unsigned)xv < 96u)
                        ? in[(size_t)cc * LL + yy * 96 + xv] : 0.0f;
            tile[r][cc][col] = val;
        }
    }
    __syncthreads();

    {
        int pxl = tid >> 3, sub = tid & 7;
        float ss = 0.0f;
        #pragma unroll
        for (int cc = 0; cc < 4; ++cc) {
            int c = sub * 4 + cc;
            #pragma unroll
            for (int u = 0; u < 3; ++u)
                #pragma unroll
                for (int v = 0; v < 3; ++v) {
                    float val = tile[u][c][pxl + v];
                    ss = fmaf(val, val, ss);
                }
        }
        ss += __shfl_xor(ss, 1);
        ss += __shfl_xor(ss, 2);
        ss += __shfl_xor(ss, 4);
        if (sub == 0) inv_s[pxl] = 1.0f / fmaxf(sqrtf(ss), 1e-12f);
    }
    __syncthreads();

    #pragma unroll 1
    for (int it = 0; it < 9; ++it) {
        int e = it * 256 + tid;
        int pxl = e / 72, dc = e - pxl * 72;
        int l = l0 + pxl;
        float inv = inv_s[pxl];
        float4 o; float* op = &o.x;
        #pragma unroll
        for (int i = 0; i < 4; ++i) {
            int d = dc * 4 + i;
            int c = d / 9, rm = d - c * 9;
            int u = rm / 3, v = rm - u * 3;
            op[i] = tile[u][c][pxl + v] * inv;
        }
        *(float4*)(o32 + (size_t)l * D9 + dc * 4) = o;
        unsigned short b4[4];
        #pragma unroll
        for (int i = 0; i < 4; ++i) b4[i] = f2bf(op[i]);
        *(uint2*)(obf + (size_t)l * D9 + dc * 4) = *(uint2*)b4;
    }
}

// ---------------- MFMA similarity + med3-packed streaming top-6 per key-split ----------------
__global__ __launch_bounds__(256, 2) void topk_mfma_kernel(
    const unsigned short* __restrict__ qn_bf, const unsigned short* __restrict__ kn_bf,
    float* __restrict__ valsQ)
{
    __shared__ unsigned short ks[2][32 * KROW];

    int tid  = threadIdx.x;
    int lane = tid & 63;
    int col = lane & 31, khalf = lane >> 5;
    int qtile = blockIdx.x >> 5;
    int split = blockIdx.x & 31;
    int q0w = qtile * 256 + (tid >> 6) * 64;
    int key0 = split * KEYS_PER_SPLIT;

    short8 qf[2][18];
    #pragma unroll
    for (int b = 0; b < 2; ++b) {
        const unsigned short* qrow = qn_bf + (size_t)(q0w + b*32 + col) * D9 + khalf * 8;
        #pragma unroll
        for (int dg = 0; dg < 18; ++dg)
            qf[b][dg] = *(const short8*)(qrow + dg * 16);
    }

    float lv0[NK], lv1[NK];
    #pragma unroll
    for (int s = 0; s < NK; ++s) { lv0[s] = -INFINITY; lv1[s] = -INFINITY; }

    const char* kg = (const char*)kn_bf;
    uint4 pre[5];

    #pragma unroll
    for (int c0 = 0; c0 < 5; ++c0) {
        int c = tid + c0 * 256;
        if (c < CHUNKS) {
            int key = c / 36, off = c - key * 36;
            pre[c0] = *(const uint4*)(kg + (size_t)(key0 + key) * 576 + off * 16);
        }
    }
    #pragma unroll
    for (int c0 = 0; c0 < 5; ++c0) {
        int c = tid + c0 * 256;
        if (c < CHUNKS) {
            int key = c / 36, off = c - key * 36;
            char* d = (char*)ks[0] + key * (KROW*2) + off * 16;
            *(uint2*)d       = *(uint2*)&pre[c0];
            *(uint2*)(d + 8) = *((uint2*)&pre[c0] + 1);
        }
    }
    __syncthreads();

    for (int p = 0; p < PASSES; ++p) {
        if (p + 1 < PASSES) {
            #pragma unroll
            for (int c0 = 0; c0 < 5; ++c0) {
                int c = tid + c0 * 256;
                if (c < CHUNKS) {
                    int key = c / 36, off = c - key * 36;
                    pre[c0] = *(const uint4*)(kg + (size_t)(key0 + (p+1)*32 + key) * 576 + off * 16);
                }
            }
        }

        f32x16 acc0 = {}, acc1 = {};
        const char* kb = (const char*)ks[p & 1] + (size_t)col * (KROW*2) + khalf * 16;
        #pragma unroll
        for (int dg = 0; dg < 18; ++dg) {
            short8 af;
            *(uint2*)&af       = *(const uint2*)(kb + dg * 32);
            *((uint2*)&af + 1) = *(const uint2*)(kb + dg * 32 + 8);
            acc0 = __builtin_amdgcn_mfma_f32_32x32x16_bf16(af, qf[0][dg], acc0, 0, 0, 0);
            acc1 = __builtin_amdgcn_mfma_f32_32x32x16_bf16(af, qf[1][dg], acc1, 0, 0, 0);
        }

        int lbase = p * 32 + 4 * khalf;
        #pragma unroll
        for (int r = 0; r < 16; ++r) {
            unsigned lkey = (unsigned)(lbase + (r & 3) + 8 * (r >> 2));
            ins_med3<NK>(lv0, asf((asu(acc0[r]) & 0xFFFFFE00u) | lkey));
            ins_med3<NK>(lv1, asf((asu(acc1[r]) & 0xFFFFFE00u) | lkey));
        }

        if (p + 1 < PASSES) {
            #pragma unroll
            for (int c0 = 0; c0 < 5; ++c0) {
                int c = tid + c0 * 256;
                if (c < CHUNKS) {
                    int key = c / 36, off = c - key * 36;
                    char* d = (char*)ks[(p+1) & 1] + key * (KROW*2) + off * 16;
                    *(uint2*)d       = *(uint2*)&pre[c0];
                    *(uint2*)(d + 8) = *((uint2*)&pre[c0] + 1);
                }
            }
        }
        __syncthreads();
    }

    #pragma unroll
    for (int b = 0; b < 2; ++b) {
        float* lv = b ? lv1 : lv0;
        float pv[NK];
        #pragma unroll
        for (int s = 0; s < NK; ++s) pv[s] = __shfl_xor(lv[s], 32);
        #pragma unroll
        for (int s = 0; s < NK; ++s) ins_med3<NK>(lv, pv[s]);
        if (lane < 32) {
            int q = q0w + b * 32 + col;
            float* vq = valsQ + (size_t)q * CPQ + split * NK;
            #pragma unroll
            for (int s = 0; s < NK; ++s) vq[s] = lv[s];
        }
    }
}

// -------- 32 lanes/query: packed merge -> top-8 candidates -> exact fp32 re-rank --------
__global__ __launch_bounds__(256) void rerank_kernel(
    const float* __restrict__ valsQ,
    const float* __restrict__ qn_f32, const float* __restrict__ kn_f32,
    float* __restrict__ vals, int* __restrict__ idxs)
{
    int tid = threadIdx.x;
    int lane = tid & 63;
    int half = lane >> 5, l32 = lane & 31;
    int q = blockIdx.x * 8 + (tid >> 6) * 2 + half;

    const float* vq = valsQ + (size_t)q * CPQ + l32 * NK;
    float v[NK];
    #pragma unroll
    for (int s = 0; s < NK; ++s) v[s] = vq[s];

    int ckey[NCAND];
    #pragma unroll
    for (int it = 0; it < NCAND; ++it) {
        float cv = v[0];
        int cl = l32;
        #pragma unroll
        for (int st = 1; st < 32; st <<= 1) {
            float ov = __shfl_xor(cv, st);
            int ol = __shfl_xor(cl, st);
            if (ov > cv || (ov == cv && ol < cl)) { cv = ov; cl = ol; }
        }
        ckey[it] = cl * KEYS_PER_SPLIT + (int)(asu(cv) & 0x1FFu);
        if (cl == l32) {
            #pragma unroll
            for (int s = 0; s < NK-1; ++s) v[s] = v[s+1];
            v[NK-1] = -INFINITY;
        }
    }

    int r = l32 >> 2, part = l32 & 3;
    const float4* qr = (const float4*)(qn_f32 + (size_t)q * D9) + part * 18;
    const float4* kr = (const float4*)(kn_f32 + (size_t)ckey[r] * D9) + part * 18;
    float s0 = 0.f, s1 = 0.f, s2 = 0.f, s3 = 0.f;
    #pragma unroll
    for (int i2 = 0; i2 < 18; ++i2) {
        float4 a = qr[i2], b = kr[i2];
        s0 = fmaf(a.x, b.x, s0); s1 = fmaf(a.y, b.y, s1);
        s2 = fmaf(a.z, b.z, s2); s3 = fmaf(a.w, b.w, s3);
    }
    float sc = (s0 + s1) + (s2 + s3);
    sc += __shfl_xor(sc, 1);
    sc += __shfl_xor(sc, 2);

    float bv[TOPK]; int bi[TOPK];
    #pragma unroll
    for (int s = 0; s < TOPK; ++s) { bv[s] = -INFINITY; bi[s] = 0x7fffffff; }
    #pragma unroll
    for (int cc = 0; cc < NCAND; ++cc) {
        float sv = __shfl(sc, half * 32 + cc * 4);
        insert_tb<TOPK>(bv, bi, sv, ckey[cc]);
    }
    if (l32 == 0) {
        #pragma unroll
        for (int s = 0; s < TOPK; ++s) {
            vals[(size_t)s * LL + q] = bv[s];
            idxs[(size_t)s * LL + q] = bi[s];
        }
    }
}

// ------------- epilogue: wave-per-pixel, lanes over channels, coalesced gathers -------------
__global__ __launch_bounds__(256) void gather_out_kernel(
    const float* __restrict__ xT, const float* __restrict__ feat,
    const float* __restrict__ vals, const int* __restrict__ idxs,
    float* __restrict__ out)
{
    int wave = threadIdx.x >> 6, lane = threadIdx.x & 63;
    int pix = blockIdx.x * 4 + wave;
    int y = pix / WW, x0 = pix - y * WW;
    float acc = 0.0f;
    #pragma unroll 1
    for (int s = 1; s < TOPK; ++s) {
        float S = vals[(size_t)s * LL + pix] * (1.0f/9.0f);
        #pragma unroll
        for (int i = 0; i < 3; ++i) {
            int qy = y + 1 - i;
            #pragma unroll
            for (int j = 0; j < 3; ++j) {
                int qx = x0 + 1 - j;
                if ((unsigned)qy < 96u && (unsigned)qx < 96u) {
                    int l = idxs[(size_t)s * LL + qy * WW + qx];
                    int yl = l / WW, xl = l - yl * WW;
                    int sy = yl + i - 1, sx = xl + j - 1;
                    if ((unsigned)sy < 96u && (unsigned)sx < 96u)
                        acc = fmaf(S, xT[(size_t)(sy * WW + sx) * 64 + lane], acc);
                }
            }
        }
    }
    out[(size_t)lane * LL + pix] = feat[(size_t)lane * LL + pix]
                                 + xT[(size_t)pix * 64 + lane] + acc * 0.25f;
}

extern "C" void kernel_launch(void* const* d_in, const int* in_sizes, int n_in,
                              void* d_out, int out_size, void* d_ws, size_t ws_size,
                              hipStream_t stream)
{
    (void)in_sizes; (void)n_in; (void)out_size; (void)ws_size;
    const float* x  = (const float*)d_in[0];
    const float* W1 = (const float*)d_in[1];
    const float* b1 = (const float*)d_in[2];
    const float* W2 = (const float*)d_in[3];
    const float* b2 = (const float*)d_in[4];
    const float* Wq = (const float*)d_in[5];
    const float* bq = (const float*)d_in[6];
    const float* Wk = (const float*)d_in[7];
    const float* bk = (const float*)d_in[8];
    float* out = (float*)d_out;

    char* p = (char*)d_ws;
    float* xpad   = (float*)p;            p += (size_t)64 * PCH * 4;
    float* c1pad  = (float*)p;            p += (size_t)64 * PCH * 4;
    float* feat   = (float*)p;            p += (size_t)64 * LL * 4;
    float* xT     = (float*)p;            p += (size_t)64 * LL * 4;
    float* qq     = (float*)p;            p += (size_t)32 * LL * 4;
    float* kk     = (float*)p;            p += (size_t)32 * LL * 4;
    float* qn_f32 = (float*)p;            p += (size_t)LL * D9 * 4;
    float* kn_f32 = (float*)p;            p += (size_t)LL * D9 * 4;
    unsigned short* qn_bf = (unsigned short*)p;  p += (size_t)LL * D9 * 2;
    unsigned short* kn_bf = (unsigned short*)p;  p += (size_t)LL * D9 * 2;
    float* valsQ  = (float*)p;            p += (size_t)LL * CPQ * 4;
    float* vals   = (float*)p;            p += (size_t)TOPK * LL * 4;
    int*   idxs   = (int*)p;              p += (size_t)TOPK * LL * 4;

    pad_init_kernel<<<dim3(2401, 2), 256, 0, stream>>>(x, xpad, c1pad);
    conv_stage1_kernel<<<dim3(18, 32), 256, 0, stream>>>(xpad, W1, b1, c1pad, Wq, bq, Wk, bk, qq, kk);
    unfold_norm_kernel<<<dim3(288, 2), 256, 0, stream>>>(qq, qn_f32, qn_bf, kk, kn_f32, kn_bf);
    topk_mfma_kernel<<<36 * KSPLIT, 256, 0, stream>>>(qn_bf, kn_bf, valsQ);
    conv2_kernel<<<dim3(18, 32), 256, 0, stream>>>(c1pad, W2, b2, feat);
    transpose_x_kernel<<<144, 256, 0, stream>>>(x, xT);
    rerank_kernel<<<LL / 8, 256, 0, stream>>>(valsQ, qn_f32, kn_f32, vals, idxs);
    gather_out_kernel<<<LL / 4, 256, 0, stream>>>(xT, feat, vals, idxs, out);
}